// Round 1
// baseline (181.954 us; speedup 1.0000x reference)
//
#include <hip/hip_runtime.h>

#define BATCH   256
#define NCOL    576
#define MROW    144
#define ZLIFT   24
#define NIT     3
#define ROW_DEG 15
#define NEDGE   (MROW * ROW_DEG)   // 2160

// Kernel 1: extract column indices of the 15 ones per check row from dense H.
__global__ void build_cols_kernel(const int* __restrict__ H, int* __restrict__ cols) {
    int m = blockIdx.x * blockDim.x + threadIdx.x;
    if (m >= MROW) return;
    const int* row = H + (size_t)m * NCOL;
    int cnt = 0;
    for (int n = 0; n < NCOL; ++n) {
        if (row[n] != 0) {
            if (cnt < ROW_DEG) cols[m * ROW_DEG + cnt] = n;
            ++cnt;
        }
    }
}

// Kernel 2: one block per frame. Offset-min-sum LDPC decode, all state in LDS.
__global__ __launch_bounds__(256) void ldpc_decode_kernel(
    const float* __restrict__ r,
    const float* __restrict__ alpha,
    const float* __restrict__ beta,
    const int*   __restrict__ cols,
    float*       __restrict__ out)
{
    __shared__ float r_s[NCOL];
    __shared__ float colsum[NCOL];
    __shared__ float M_s[NEDGE];
    __shared__ float E_s[NEDGE];
    __shared__ int   c_s[NEDGE];

    const int b   = blockIdx.x;
    const int tid = threadIdx.x;

    // Stage channel LLRs and edge column indices.
    for (int n = tid; n < NCOL; n += 256) r_s[n] = r[(size_t)b * NCOL + n];
    for (int e = tid; e < NEDGE; e += 256) c_s[e] = cols[e];
    __syncthreads();

    // Initial v->c messages: M[e] = r[col[e]]  (Hf * r on edges).
    for (int e = tid; e < NEDGE; e += 256) M_s[e] = r_s[c_s[e]];

    for (int it = 0; it < NIT; ++it) {
        for (int n = tid; n < NCOL; n += 256) colsum[n] = 0.0f;
        __syncthreads();   // M_s ready (first iter) / colsum zeroed

        if (tid < MROW) {
            const int m = tid;
            float min1 = INFINITY, min2 = INFINITY;
            int   kmin = -1;
            float sprod = 1.0f;
            float vals[ROW_DEG];
            // Pass 1: min-2 magnitudes (first-occurrence argmin == top_k
            // tie-break), and row sign product (sign(0)=0, like jnp.sign).
            #pragma unroll
            for (int k = 0; k < ROW_DEG; ++k) {
                float v = M_s[m * ROW_DEG + k];
                vals[k] = v;
                float av = fabsf(v);
                float s  = (v > 0.0f) ? 1.0f : ((v < 0.0f) ? -1.0f : 0.0f);
                sprod *= s;
                if (av < min1)      { min2 = min1; min1 = av; kmin = k; }
                else if (av < min2) { min2 = av; }
            }
            const int arow = (m / ZLIFT) * (NCOL / ZLIFT);
            // Pass 2: extrinsic messages E, accumulate column sums.
            #pragma unroll
            for (int k = 0; k < ROW_DEG; ++k) {
                const int e = m * ROW_DEG + k;
                const int n = c_s[e];
                float v  = vals[k];
                float s  = (v > 0.0f) ? 1.0f : ((v < 0.0f) ? -1.0f : 0.0f);
                const int sc = (arow + n / ZLIFT) * NIT + it;
                float a  = alpha[sc];
                float bt = beta[sc];
                float eabs = (k == kmin) ? min2 : min1;
                float mag  = eabs - bt;
                if (mag < 0.0f) mag = 0.0f;
                float E = a * (sprod * s) * mag;
                E_s[e] = E;
                atomicAdd(&colsum[n], E);
            }
        }
        __syncthreads();   // colsum + E_s complete

        if (it < NIT - 1) {
            // Variable -> check: sum-minus-self.
            for (int e = tid; e < NEDGE; e += 256) {
                const int n = c_s[e];
                M_s[e] = r_s[n] + colsum[n] - E_s[e];
            }
            __syncthreads();
        }
    }

    // Posterior LLRs.
    for (int n = tid; n < NCOL; n += 256)
        out[(size_t)b * NCOL + n] = r_s[n] + colsum[n];
}

extern "C" void kernel_launch(void* const* d_in, const int* in_sizes, int n_in,
                              void* d_out, int out_size, void* d_ws, size_t ws_size,
                              hipStream_t stream) {
    const float* r     = (const float*)d_in[0];
    const float* alpha = (const float*)d_in[1];
    const float* beta  = (const float*)d_in[2];
    const int*   H     = (const int*)d_in[3];
    float* out = (float*)d_out;
    int*   cols = (int*)d_ws;   // NEDGE ints

    build_cols_kernel<<<1, 256, 0, stream>>>(H, cols);
    ldpc_decode_kernel<<<BATCH, 256, 0, stream>>>(r, alpha, beta, cols, out);
}

// Round 2
// 81.704 us; speedup vs baseline: 2.2270x; 2.2270x over previous
//
#include <hip/hip_runtime.h>

#define BATCH   256
#define NCOL    576
#define MROW    144
#define ZLIFT   24
#define NIT     3
#define ROW_DEG 15
#define NEDGE   (MROW * ROW_DEG)   // 2160

// Kernel 1: one wave per check row. Ballot+popcount compaction of the 15
// ones per row, preserving ascending column order (argmin tie-break needs it).
__global__ __launch_bounds__(256) void build_cols_kernel(
    const int* __restrict__ H, int* __restrict__ cols)
{
    const int wave = (blockIdx.x * blockDim.x + threadIdx.x) >> 6;
    const int lane = threadIdx.x & 63;
    if (wave >= MROW) return;
    const int* row = H + (size_t)wave * NCOL;
    int base = 0;
    #pragma unroll
    for (int c0 = 0; c0 < NCOL; c0 += 64) {
        const int n = c0 + lane;
        const int present = (row[n] != 0) ? 1 : 0;
        const unsigned long long mask = __ballot(present);
        if (present) {
            const int rank = __popcll(mask & ((1ull << lane) - 1ull));
            const int idx = base + rank;
            if (idx < ROW_DEG) cols[wave * ROW_DEG + idx] = n;
        }
        base += __popcll(mask);
    }
}

// Kernel 2: one block per frame. Offset-min-sum LDPC decode, all state in LDS.
__global__ __launch_bounds__(256) void ldpc_decode_kernel(
    const float* __restrict__ r,
    const float* __restrict__ alpha,
    const float* __restrict__ beta,
    const int*   __restrict__ cols,
    float*       __restrict__ out)
{
    __shared__ float r_s[NCOL];
    __shared__ float colsum[NCOL];
    __shared__ float M_s[NEDGE];
    __shared__ float E_s[NEDGE];
    __shared__ int   c_s[NEDGE];

    const int b   = blockIdx.x;
    const int tid = threadIdx.x;

    // Stage channel LLRs and edge column indices.
    for (int n = tid; n < NCOL; n += 256) r_s[n] = r[(size_t)b * NCOL + n];
    for (int e = tid; e < NEDGE; e += 256) c_s[e] = cols[e];
    __syncthreads();

    // Initial v->c messages: M[e] = r[col[e]]  (Hf * r on edges).
    for (int e = tid; e < NEDGE; e += 256) M_s[e] = r_s[c_s[e]];

    for (int it = 0; it < NIT; ++it) {
        for (int n = tid; n < NCOL; n += 256) colsum[n] = 0.0f;
        __syncthreads();   // M_s ready (first iter) / colsum zeroed

        if (tid < MROW) {
            const int m = tid;
            float min1 = INFINITY, min2 = INFINITY;
            int   kmin = -1;
            float sprod = 1.0f;
            float vals[ROW_DEG];
            // Pass 1: min-2 magnitudes (first-occurrence argmin == top_k
            // tie-break), and row sign product (sign(0)=0, like jnp.sign).
            #pragma unroll
            for (int k = 0; k < ROW_DEG; ++k) {
                float v = M_s[m * ROW_DEG + k];
                vals[k] = v;
                float av = fabsf(v);
                float s  = (v > 0.0f) ? 1.0f : ((v < 0.0f) ? -1.0f : 0.0f);
                sprod *= s;
                if (av < min1)      { min2 = min1; min1 = av; kmin = k; }
                else if (av < min2) { min2 = av; }
            }
            const int arow = (m / ZLIFT) * (NCOL / ZLIFT);
            // Pass 2: extrinsic messages E, accumulate column sums.
            #pragma unroll
            for (int k = 0; k < ROW_DEG; ++k) {
                const int e = m * ROW_DEG + k;
                const int n = c_s[e];
                float v  = vals[k];
                float s  = (v > 0.0f) ? 1.0f : ((v < 0.0f) ? -1.0f : 0.0f);
                const int sc = (arow + n / ZLIFT) * NIT + it;
                float a  = alpha[sc];
                float bt = beta[sc];
                float eabs = (k == kmin) ? min2 : min1;
                float mag  = eabs - bt;
                if (mag < 0.0f) mag = 0.0f;
                float E = a * (sprod * s) * mag;
                E_s[e] = E;
                atomicAdd(&colsum[n], E);
            }
        }
        __syncthreads();   // colsum + E_s complete

        if (it < NIT - 1) {
            // Variable -> check: sum-minus-self.
            for (int e = tid; e < NEDGE; e += 256) {
                const int n = c_s[e];
                M_s[e] = r_s[n] + colsum[n] - E_s[e];
            }
            __syncthreads();
        }
    }

    // Posterior LLRs.
    for (int n = tid; n < NCOL; n += 256)
        out[(size_t)b * NCOL + n] = r_s[n] + colsum[n];
}

extern "C" void kernel_launch(void* const* d_in, const int* in_sizes, int n_in,
                              void* d_out, int out_size, void* d_ws, size_t ws_size,
                              hipStream_t stream) {
    const float* r     = (const float*)d_in[0];
    const float* alpha = (const float*)d_in[1];
    const float* beta  = (const float*)d_in[2];
    const int*   H     = (const int*)d_in[3];
    float* out = (float*)d_out;
    int*   cols = (int*)d_ws;   // NEDGE ints

    // 144 waves, one per row: 144*64 = 9216 threads = 36 blocks of 256.
    build_cols_kernel<<<(MROW * 64 + 255) / 256, 256, 0, stream>>>(H, cols);
    ldpc_decode_kernel<<<BATCH, 256, 0, stream>>>(r, alpha, beta, cols, out);
}